// Round 8
// baseline (1846.769 us; speedup 1.0000x reference)
//
#include <hip/hip_runtime.h>
#include <math.h>

#define HH 512
#define WW 1024
#define HWSZ (HH*WW)
#define BB 4
#define TY 8
#define NP (TY/2)
#define KSIG 11.541560327111707
#define DD_OFF (BB*3*HWSZ)

typedef float v2f __attribute__((ext_vector_type(2)));

// One group of source columns (compile-time rx offsets) for one source row.
// Output rows are processed in PAIRS (k=2p,2p+1) with packed-f32 math:
//   den2 = pk_fma(C2, rc, rr);  w2 = (rcp, rcp);  accums via pk_fma/pk_add.
// Footprint masking is baked into the table sentinels (D=1e30, C=+inf ->
// w=0, no circle) -> branchless evals; only a uniform per-pair m-range guard.
template<int... RX>
__device__ __forceinline__ void group_eval(
    const float* __restrict__ pd, const float* __restrict__ p0,
    const float* __restrict__ p1, const float* __restrict__ p2,
    int x, bool edge, int ryy, const float4 (*T4)[7],
    v2f* aW, v2f* aR, v2f* aG, v2f* aB, v2f* aD)
{
    constexpr int N = sizeof...(RX);
    constexpr int rxs[N] = { RX... };

    float d[N], i0[N], i1[N], i2[N];
#pragma unroll
    for (int j = 0; j < N; ++j) {
        const int rx = rxs[j];
        if (edge) {
            const int col = x + rx;
            const bool valid = (unsigned)col < (unsigned)WW;
            const int cc  = col < 0 ? 0 : (col > WW-1 ? WW-1 : col);
            const int cof = cc - x;                 // clamped (safe) offset
            float dv = pd[cof];
            d[j]  = valid ? dv : 0.0f;              // OOB: w<=3.4e-4, no circle
            i0[j] = p0[cof]; i1[j] = p1[cof]; i2[j] = p2[cof];
        } else {
            d[j] = pd[rx]; i0[j] = p0[rx]; i1[j] = p1[rx]; i2[j] = p2[rx];
        }
    }
    float r[N], rr[N], rc[N], di[N];
#pragma unroll
    for (int j = 0; j < N; ++j) {
        r[j]  = fabsf(d[j]);                        // folds to src modifier
        rr[j] = fmaxf(d[j]*d[j], 1.0f);
        rc[j] = rr[j] * __builtin_amdgcn_exp2f(r[j] * (float)(-KSIG));
        di[j] = truncf(d[j]);                       // == (float)(int)defocus
    }
#pragma unroll
    for (int p = 0; p < NP; ++p) {
        const int m = ryy - 2*p;                    // ay0=|m|, ay1=|m-1|
        if (m < -6 || m > 7) continue;              // uniform: both rows dead
        const float4* __restrict__ prow = T4[m + 6];
#pragma unroll
        for (int j = 0; j < N; ++j) {
            constexpr int rxs2[N] = { RX... };
            const int rx = rxs2[j];
            const int ax = rx < 0 ? -rx : rx;
            const float4 t = prow[ax];              // ds_read_b128 broadcast
            const v2f C2 = { t.z, t.w };
            const v2f den = C2 * rc[j] + rr[j];     // v_pk_fma_f32
            const v2f w = { __builtin_amdgcn_rcpf(den.x),
                            __builtin_amdgcn_rcpf(den.y) };
            aW[p] += w;                             // v_pk_add_f32
            aR[p] += w * i0[j];                     // v_pk_fma_f32
            aG[p] += w * i1[j];
            aB[p] += w * i2[j];
            const v2f cand = { r[j] >= t.x ? di[j] : -1e30f,
                               r[j] >= t.y ? di[j] : -1e30f };
            aD[p].x = fmaxf(aD[p].x, cand.x);
            aD[p].y = fmaxf(aD[p].y, cand.y);
        }
    }
}

__global__ __launch_bounds__(256, 4)
void bokeh_kernel(const float* __restrict__ img,
                  const float* __restrict__ defo,
                  float* __restrict__ out)
{
    // T4[m+6][ax] = (D(|m|,ax), D(|m-1|,ax), C(|m|,ax), C(|m-1|,ax)),
    // D correctly rounded (fp64 sqrt), C = 2^(K*D).  Sentinel (1e30, +inf)
    // where ay>6 or ay^2+ax^2>49 -> that half contributes exactly nothing.
    __shared__ float4 T4[14][7];
    {
        const int t = threadIdx.x;
        if (t < 14*7) {
            const int mi = t / 7, ax = t - mi*7;
            const int m  = mi - 6;
            const int a0 = m < 0 ? -m : m;
            const int a1 = (m-1) < 0 ? -(m-1) : (m-1);
            float D0 = 1e30f, C0 = __builtin_inff();
            float D1 = 1e30f, C1 = __builtin_inff();
            if (a0 <= 6 && a0*a0 + ax*ax <= 49) {
                D0 = (float)sqrt((double)(a0*a0 + ax*ax));
                C0 = (float)exp2((double)D0 * KSIG);
            }
            if (a1 <= 6 && a1*a1 + ax*ax <= 49) {
                D1 = (float)sqrt((double)(a1*a1 + ax*ax));
                C1 = (float)exp2((double)D1 * KSIG);
            }
            T4[mi][ax] = make_float4(D0, D1, C0, C1);
        }
    }
    __syncthreads();

    const int lane = threadIdx.x & 63;
    const int wv   = threadIdx.x >> 6;
    const int bx   = blockIdx.x;
    const int x    = bx*64 + lane;                 // lane = x -> coalesced
    const int y0   = blockIdx.y*(4*TY) + wv*TY;    // TY output rows per thread
    const int b    = blockIdx.z;
    const bool edge = (bx == 0) || (bx == WW/64 - 1);   // wave-uniform

    const float* __restrict__ dP = defo + (size_t)b*HWSZ;
    const float* __restrict__ c0 = img + (size_t)(b*3+0)*HWSZ;
    const float* __restrict__ c1 = img + (size_t)(b*3+1)*HWSZ;
    const float* __restrict__ c2 = img + (size_t)(b*3+2)*HWSZ;

    v2f aW[NP], aR[NP], aG[NP], aB[NP], aD[NP];
#pragma unroll
    for (int p=0;p<NP;++p){
        aW[p]=(v2f){0.f,0.f}; aR[p]=(v2f){0.f,0.f}; aG[p]=(v2f){0.f,0.f};
        aB[p]=(v2f){0.f,0.f}; aD[p]=(v2f){-1e30f,-1e30f};
    }

#pragma unroll 1
    for (int ryy = -6; ryy <= TY+5; ++ryy) {       // source rows (runtime loop)
        const int sy = y0 + ryy;
        if ((unsigned)sy >= (unsigned)HH) continue;    // uniform (zero pad)
        const int rb = sy*WW + x;
        const float* __restrict__ pd = dP + rb;
        const float* __restrict__ p0 = c0 + rb;
        const float* __restrict__ p1 = c1 + rb;
        const float* __restrict__ p2 = c2 + rb;
        group_eval<-6,-5,-4,-3,-2>(pd,p0,p1,p2,x,edge,ryy,T4,aW,aR,aG,aB,aD);
        group_eval<-1, 0, 1, 2, 3>(pd,p0,p1,p2,x,edge,ryy,T4,aW,aR,aG,aB,aD);
        group_eval< 4, 5, 6>      (pd,p0,p1,p2,x,edge,ryy,T4,aW,aR,aG,aB,aD);
    }

#pragma unroll
    for (int p=0;p<NP;++p) {
        const float invx = __builtin_amdgcn_rcpf(aW[p].x);  // aW >= ~0.0139
        const float invy = __builtin_amdgcn_rcpf(aW[p].y);
        const int yA = y0 + 2*p, yB = yA + 1;
        const size_t oA = (size_t)yA*WW + x, oB = (size_t)yB*WW + x;
        out[(size_t)(b*3+0)*HWSZ + oA] = aR[p].x*invx;
        out[(size_t)(b*3+1)*HWSZ + oA] = aG[p].x*invx;
        out[(size_t)(b*3+2)*HWSZ + oA] = aB[p].x*invx;
        out[DD_OFF + (size_t)b*HWSZ + oA] = aD[p].x;
        out[(size_t)(b*3+0)*HWSZ + oB] = aR[p].y*invy;
        out[(size_t)(b*3+1)*HWSZ + oB] = aG[p].y*invy;
        out[(size_t)(b*3+2)*HWSZ + oB] = aB[p].y*invy;
        out[DD_OFF + (size_t)b*HWSZ + oB] = aD[p].y;
    }
}

extern "C" void kernel_launch(void* const* d_in, const int* in_sizes, int n_in,
                              void* d_out, int out_size, void* d_ws, size_t ws_size,
                              hipStream_t stream)
{
    const float* img  = (const float*)d_in[0];
    const float* defo = (const float*)d_in[1];
    float* out = (float*)d_out;
    bokeh_kernel<<<dim3(WW/64, HH/(4*TY), BB), dim3(256,1,1), 0, stream>>>(img, defo, out);
}